// Round 5
// baseline (233.912 us; speedup 1.0000x reference)
//
#include <hip/hip_runtime.h>

typedef __bf16 bf16x8 __attribute__((ext_vector_type(8)));
typedef float f32x4 __attribute__((ext_vector_type(4)));
typedef unsigned short u16x8 __attribute__((ext_vector_type(8)));

#define S_LEN 2048
#define NHEAD 16
#define HDIM  64
#define EMB   1024

__device__ __forceinline__ ushort f2b(float v) {
  union { float f; unsigned u; } x; x.f = v;
  unsigned r = (x.u + 0x7fffu + ((x.u >> 16) & 1u)) >> 16;
  return (ushort)r;
}

__device__ __forceinline__ ushort f2b_trunc(float v) {
  union { float f; unsigned u; } x; x.f = v;
  return (ushort)(x.u >> 16);  // pattern-matches ds_write_b16_d16_hi
}

// async global->LDS, 16B per lane; LDS dest = wave-uniform base + lane*16
typedef const __attribute__((address_space(1))) unsigned int* gp1_t;
typedef __attribute__((address_space(3))) unsigned int* lp3_t;
__device__ __forceinline__ void gld16(const ushort* g, const ushort* l) {
  __builtin_amdgcn_global_load_lds((gp1_t)(unsigned long long)(uintptr_t)g,
                                   (lp3_t)(unsigned int)(uintptr_t)l, 16, 0, 0);
}

__device__ __forceinline__ void barf() {
  asm volatile("" ::: "memory");
  __builtin_amdgcn_s_barrier();
  asm volatile("" ::: "memory");
}

// ---------- fused prep: cast x -> bf16 (z==4) + transpose/cast weights (z<4) ----------
__global__ __launch_bounds__(256) void prep_kernel(
    const float* __restrict__ x, const float* __restrict__ W0,
    const float* __restrict__ W1, const float* __restrict__ W2,
    const float* __restrict__ W3, ushort* __restrict__ xb,
    ushort* __restrict__ Wt0, ushort* __restrict__ Wt1,
    ushort* __restrict__ Wt2, ushort* __restrict__ Wt3, float scale0) {
  const int z = blockIdx.z;
  if (z == 4) {  // x cast: 1024 blocks x 8192 floats
    size_t base = ((size_t)(blockIdx.y * 32 + blockIdx.x)) * 8192 + threadIdx.x * 4;
#pragma unroll
    for (int i = 0; i < 8; ++i) {
      float4 v = *(const float4*)(x + base + i * 1024);
      ushort4 o;
      o.x = f2b(v.x); o.y = f2b(v.y); o.z = f2b(v.z); o.w = f2b(v.w);
      *(ushort4*)(xb + base + i * 1024) = o;
    }
    return;
  }
  __shared__ float t[32][33];
  const float* W = z == 0 ? W0 : (z == 1 ? W1 : (z == 2 ? W2 : W3));
  ushort* Wt = z == 0 ? Wt0 : (z == 1 ? Wt1 : (z == 2 ? Wt2 : Wt3));
  const float scale = z == 0 ? scale0 : 1.0f;
  int k0 = blockIdx.x * 32, n0 = blockIdx.y * 32;
  int c = threadIdx.x & 31, r0 = threadIdx.x >> 5;
#pragma unroll
  for (int i = 0; i < 4; ++i) {
    int r = r0 + i * 8;
    t[r][c] = W[(size_t)(k0 + r) * EMB + n0 + c];
  }
  __syncthreads();
#pragma unroll
  for (int i = 0; i < 4; ++i) {
    int r = r0 + i * 8;
    Wt[(size_t)(n0 + r) * EMB + k0 + c] = f2b(t[c][r] * scale);
  }
}

// ---------------- GEMM v5 (unchanged from round 4, passing) ----------------
// 128x256 tile, BK=64, 8 waves (2M x 4N, per-wave 64x64), 512 threads.
// Swizzled 128B-row LDS (0 bank conflicts), 3-slot ring, counted vmcnt,
// register-double-buffered fragments, ONE barrier per K-tile with
// vmcnt(6)+lgkmcnt(0) BEFORE the barrier (cross-wave staging guarantee).
template <int EPI>
__global__ __launch_bounds__(512, 2) void gemm8_kernel(
    const ushort* __restrict__ A, const ushort* __restrict__ Bt,
    ushort* __restrict__ outQ, ushort* __restrict__ outK, ushort* __restrict__ outVt,
    float* __restrict__ outF, const float* __restrict__ bias) {
  // A slots: 3 x [128][64] ushort at 0      (slot s at s*8192 ushorts, 16KB)
  // B slots: 3 x [256][64] ushort at 24576  (slot s at 24576 + s*16384, 32KB)
  __shared__ ushort lds8[73728];  // 144 KiB
  const int tid = threadIdx.x;
  const int wave = tid >> 6, lane = tid & 63, ln = lane & 15, quad = lane >> 4;
  const int wm = wave >> 2, wn = wave & 3;
  const long m0 = (long)blockIdx.x * 128, n0 = (long)blockIdx.y * 256;
  constexpr int K = EMB, KT = K / 64;  // 16 K-tiles

  // ---- staging addresses (pre-swizzled global source, linear LDS dest) ----
  const int srow = tid >> 3;                         // 0..63
  const int scol = ((tid & 7) ^ (srow & 7)) * 8;     // swizzled ushort col
  const ushort* srcA = A + (m0 + srow) * (long)K + scol;   // +t*64 +ld*64*K
  const ushort* srcB = Bt + (n0 + srow) * (long)K + scol;

#define STG_A(t, s)                                                            \
  do {                                                                         \
    gld16(srcA + (t) * 64,               lds8 + (s) * 8192 + tid * 8);         \
    gld16(srcA + (t) * 64 + 64 * K,      lds8 + (s) * 8192 + 4096 + tid * 8);  \
  } while (0)
#define STG_B(t, s)                                                            \
  do {                                                                         \
    gld16(srcB + (t) * 64,               lds8 + 24576 + (s) * 16384 + tid * 8);         \
    gld16(srcB + (t) * 64 + 64 * K,      lds8 + 24576 + (s) * 16384 + 4096 + tid * 8);  \
    gld16(srcB + (t) * 64 + 128 * K,     lds8 + 24576 + (s) * 16384 + 8192 + tid * 8);  \
    gld16(srcB + (t) * 64 + 192 * K,     lds8 + 24576 + (s) * 16384 + 12288 + tid * 8); \
  } while (0)

  // ---- fragment reads (swizzled col; row&7 == ln&7 since wm*64,mt*16 are 8-mult) ----
  const int sw = (ln & 7) * 8;

#define RD_A(F, kk, s)                                                         \
  do {                                                                         \
    const ushort* p_ = lds8 + (s) * 8192 + (wm * 64 + ln) * 64 +               \
                       (((kk) * 32 + quad * 8) ^ sw);                          \
    F[0] = *(const bf16x8*)p_;                                                 \
    F[1] = *(const bf16x8*)(p_ + 1024);                                        \
    F[2] = *(const bf16x8*)(p_ + 2048);                                        \
    F[3] = *(const bf16x8*)(p_ + 3072);                                        \
  } while (0)
#define RD_B(F, kk, s)                                                         \
  do {                                                                         \
    const ushort* p_ = lds8 + 24576 + (s) * 16384 + (wn * 64 + ln) * 64 +      \
                       (((kk) * 32 + quad * 8) ^ sw);                          \
    F[0] = *(const bf16x8*)p_;                                                 \
    F[1] = *(const bf16x8*)(p_ + 1024);                                        \
    F[2] = *(const bf16x8*)(p_ + 2048);                                        \
    F[3] = *(const bf16x8*)(p_ + 3072);                                        \
  } while (0)

#define MM16(AF, BF)                                                           \
  do {                                                                         \
    __builtin_amdgcn_s_setprio(1);                                             \
    _Pragma("unroll") for (int mt = 0; mt < 4; ++mt)                           \
        _Pragma("unroll") for (int nt = 0; nt < 4; ++nt)                       \
            acc[mt][nt] = __builtin_amdgcn_mfma_f32_16x16x32_bf16(             \
                AF[mt], BF[nt], acc[mt][nt], 0, 0, 0);                         \
    __builtin_amdgcn_s_setprio(0);                                             \
  } while (0)

  f32x4 acc[4][4] = {};
  bf16x8 afP[4], bfP[4], afN[4], bfN[4];

  // ---- prologue: stage tiles 0,1; vmcnt BEFORE barrier (cross-wave), read kk0(0) ----
  STG_A(0, 0); STG_B(0, 0);
  STG_A(1, 1); STG_B(1, 1);
  asm volatile("s_waitcnt vmcnt(6)" ::: "memory");
  barf();
  RD_A(afP, 0, 0); RD_B(bfP, 0, 0);

  // ---- main pipeline: one barrier per K-tile, reads issued under MFMA ----
#define TILE_FULL(t, s, s1, s2)                                                \
  do {                                                                         \
    STG_A((t) + 2, s2);                                                        \
    RD_A(afN, 1, s); RD_B(bfN, 1, s);                                          \
    MM16(afP, bfP);                      /* kk0 of t, overlaps RD_N */         \
    STG_B((t) + 2, s2);                                                        \
    asm volatile("s_waitcnt vmcnt(6) lgkmcnt(0)" ::: "memory");                \
    barf();                              /* after: t+1 landed for ALL waves */ \
    RD_A(afP, 0, s1); RD_B(bfP, 0, s1);  /* kk0 of t+1 */                      \
    MM16(afN, bfN);                      /* kk1 of t, overlaps RD_P */         \
  } while (0)

  for (int th = 0; th < 12; th += 3) {
    TILE_FULL(th, 0, 1, 2);
    TILE_FULL(th + 1, 1, 2, 0);
    TILE_FULL(th + 2, 2, 0, 1);
  }
  TILE_FULL(12, 0, 1, 2);
  TILE_FULL(13, 1, 2, 0);
  // tile 14 (s=2, s1=0): nothing to stage; vmcnt(0)+barrier gates tile 15
  RD_A(afN, 1, 2); RD_B(bfN, 1, 2);
  MM16(afP, bfP);
  asm volatile("s_waitcnt vmcnt(0) lgkmcnt(0)" ::: "memory");
  barf();
  RD_A(afP, 0, 0); RD_B(bfP, 0, 0);
  MM16(afN, bfN);
  // tile 15 (s=0): pure compute
  RD_A(afN, 1, 0); RD_B(bfN, 1, 0);
  MM16(afP, bfP);
  MM16(afN, bfN);

  // ---- epilogue ----
  if (EPI == 0) {
    const int sel = (int)(n0 >> 10);  // block-uniform: 1024 | 256*4
    if (sel == 2) {
      // V: write transposed [bh][d][s]; 4 regs = 4 consecutive s -> uint2
#pragma unroll
      for (int mt = 0; mt < 4; ++mt) {
        const long mbase = m0 + wm * 64 + mt * 16 + quad * 4;
        const long bb = mbase >> 11, s = mbase & 2047;
#pragma unroll
        for (int nt = 0; nt < 4; ++nt) {
          const int nn = (int)((n0 & 1023) + wn * 64 + nt * 16 + ln);
          const int h = nn >> 6, d = nn & 63;
          uint2 val;
          val.x = (unsigned)f2b(acc[mt][nt][0]) | ((unsigned)f2b(acc[mt][nt][1]) << 16);
          val.y = (unsigned)f2b(acc[mt][nt][2]) | ((unsigned)f2b(acc[mt][nt][3]) << 16);
          *(uint2*)(outVt + (((bb * NHEAD + h) * (long)HDIM + d) * S_LEN) + s) = val;
        }
      }
    } else {
      ushort* dst = sel == 0 ? outQ : outK;
#pragma unroll
      for (int mt = 0; mt < 4; ++mt) {
#pragma unroll
        for (int nt = 0; nt < 4; ++nt) {
          const int nn = (int)((n0 & 1023) + wn * 64 + nt * 16 + ln);
          const int h = nn >> 6, d = nn & 63;
#pragma unroll
          for (int r = 0; r < 4; ++r) {
            const long m = m0 + wm * 64 + mt * 16 + quad * 4 + r;
            const long bb = m >> 11, s = m & 2047;
            dst[(((bb * NHEAD + h) * S_LEN) + s) * HDIM + d] = f2b(acc[mt][nt][r]);
          }
        }
      }
    }
  } else {
#pragma unroll
    for (int mt = 0; mt < 4; ++mt) {
#pragma unroll
      for (int nt = 0; nt < 4; ++nt) {
        const long n = n0 + wn * 64 + nt * 16 + ln;
        const float bv = bias[n];
#pragma unroll
        for (int r = 0; r < 4; ++r) {
          const long m = m0 + wm * 64 + mt * 16 + quad * 4 + r;
          outF[m * (long)EMB + n] = acc[mt][nt][r] + bv;
        }
      }
    }
  }
#undef TILE_FULL
#undef MM16
#undef RD_B
#undef RD_A
#undef STG_B
#undef STG_A
}

// ---------------- flash attention, v5 ----------------
// Q,K: [bh][s][d] bf16 (Q pre-scaled by log2e/8 via Wq).  Vt: [bh][d][s] bf16.
// Y: [b][s][h][d] bf16.
// v5 change (T2 on K/V): Ks/Vs tiles are now 128B rows ([64][64] ushort) with
// XOR swizzle chunk ^= row&7, staged via pre-swizzled per-lane GLOBAL source
// + linear gld_lds dest (rule #21), read with the same XOR (row&7 == ln&7).
// Old 64B-row layout put consecutive 8-lane groups on 2 of 8 bank-slots ->
// ~4-way conflict on every K/V ds_read_b128 (6.49M conflict cycles/dispatch,
// ~5.8 cyc/read) sitting INSIDE the serial QK->exp->PV chain.  New layout is
// the conflict-free pattern proven in gemm8 (conflicts -> 0).
__global__ __launch_bounds__(256) void attn_kernel(const ushort* __restrict__ Q,
                                                   const ushort* __restrict__ Kg,
                                                   const ushort* __restrict__ Vt,
                                                   ushort* __restrict__ Y) {
  __shared__ alignas(16) ushort Ks[2][4096];  // [buf][key 64][d 64] swizzled
  __shared__ alignas(16) ushort Vs[2][4096];  // [buf][d 64][key 64] swizzled
  __shared__ alignas(16) ushort Ps[4 * 2 * 16 * 72]; // [wave][mt][16 rows][72]
  const int tid = threadIdx.x;
  const int wave = tid >> 6, lane = tid & 63, ln = lane & 15, quad = lane >> 4;
  const int bh = blockIdx.x;
  const int qb = 15 - (int)blockIdx.y;  // LPT: longest q-blocks first
  const int q0 = qb * 128;
  const size_t base = (size_t)bh * S_LEN * HDIM;
  const int ntiles = 2 * qb + 2;

  const u16x8 ob = {0x3F80, 0x3F80, 0x3F80, 0x3F80, 0x3F80, 0x3F80, 0x3F80, 0x3F80};
  const bf16x8 ones = __builtin_bit_cast(bf16x8, ob);

  bf16x8 qf[2][2];
#pragma unroll
  for (int mt = 0; mt < 2; ++mt)
#pragma unroll
    for (int ks2 = 0; ks2 < 2; ++ks2)
      qf[mt][ks2] = *(const bf16x8*)(Q + base + (size_t)(q0 + wave * 32 + mt * 16 + ln) * HDIM +
                                     ks2 * 32 + quad * 8);

  f32x4 acc[2][4] = {};
  f32x4 accl[2] = {};

  // ---- staging: pre-swizzled global source, linear LDS dest (rule #21) ----
  // chunk j = ld*256 + tid of a [64][64u] tile: row = j>>3 (srow, srow+32),
  // chunk c = tid&7; LDS(row, c) holds data(row, c ^ (row&7)).
  const int srow = tid >> 3;                        // 0..31
  const int scc  = ((tid & 7) ^ (srow & 7)) * 8;    // swizzled ushort col
  const ushort* KgS = Kg + base + (size_t)srow * HDIM + scc;   // + k*HDIM
  const ushort* VgS = Vt + base + (size_t)srow * S_LEN + scc;  // + k

  {
    gld16(KgS,                       &Ks[0][0] + tid * 8);
    gld16(KgS + 32 * HDIM,           &Ks[0][0] + 2048 + tid * 8);
    gld16(VgS,                       &Vs[0][0] + tid * 8);
    gld16(VgS + 32 * (size_t)S_LEN,  &Vs[0][0] + 2048 + tid * 8);
  }
  __syncthreads();

  ushort* Pw0 = Ps + wave * 2304;
  ushort* Pw1 = Pw0 + 1152;
  const int swW = (quad >> 1) << 4;  // P write-side swizzle: row = quad*4+r
  const int swR = (ln >> 3) << 4;    // P read-side swizzle: row = ln
  const int swL = (ln & 7) * 8;      // K/V read swizzle (row&7 == ln&7)

  for (int kt = 0; kt < ntiles; ++kt) {
    const int cur = kt & 1;
    const int k0 = kt * 64;
    if (kt + 1 < ntiles) {
      const int nb = cur ^ 1;
      const size_t k1 = (size_t)(k0 + 64);
      gld16(KgS + k1 * HDIM,                  &Ks[nb][0] + tid * 8);
      gld16(KgS + (k1 + 32) * HDIM,           &Ks[nb][0] + 2048 + tid * 8);
      gld16(VgS + k1,                         &Vs[nb][0] + tid * 8);
      gld16(VgS + 32 * (size_t)S_LEN + k1,    &Vs[nb][0] + 2048 + tid * 8);
    }
    const ushort* Kc = &Ks[cur][0];
    const ushort* Vc = &Vs[cur][0];
    const int qbase = q0 + wave * 32;

    if (k0 < qbase + 32) {
      f32x4 s0[4] = {}, s1[4] = {};
#pragma unroll
      for (int ks2 = 0; ks2 < 2; ++ks2) {
#pragma unroll
        for (int nt = 0; nt < 4; ++nt) {
          bf16x8 bk = *(const bf16x8*)(Kc + (nt * 16 + ln) * 64 +
                                       ((ks2 * 32 + quad * 8) ^ swL));
          s0[nt] = __builtin_amdgcn_mfma_f32_16x16x32_bf16(qf[0][ks2], bk, s0[nt], 0, 0, 0);
          s1[nt] = __builtin_amdgcn_mfma_f32_16x16x32_bf16(qf[1][ks2], bk, s1[nt], 0, 0, 0);
        }
      }

      if (k0 + 63 > qbase) {  // diagonal region: causal mask (also zeroes dead mt0)
        const int rowq = qbase + quad * 4;
#pragma unroll
        for (int nt = 0; nt < 4; ++nt)
#pragma unroll
          for (int r = 0; r < 4; ++r) {
            const int key = k0 + nt * 16 + ln;
            if (key > rowq + r) s0[nt][r] = -3.0e38f;
            if (key > rowq + 16 + r) s1[nt][r] = -3.0e38f;
          }
      }

      asm volatile("" ::: "memory");
#pragma unroll
      for (int nt = 0; nt < 4; ++nt) {
#pragma unroll
        for (int r = 0; r < 4; ++r) {
          float p0 = __builtin_amdgcn_exp2f(s0[nt][r]);
          float p1 = __builtin_amdgcn_exp2f(s1[nt][r]);
          const int row = (quad * 4 + r) * 72;
          const int col = (nt * 16 + ln) ^ swW;
          Pw0[row + col] = f2b_trunc(p0);
          Pw1[row + col] = f2b_trunc(p1);
        }
      }
      asm volatile("" ::: "memory");

#pragma unroll
      for (int ks2 = 0; ks2 < 2; ++ks2) {
        const int rcol = (ks2 * 32 + quad * 8) ^ swR;
        bf16x8 ap0 = *(const bf16x8*)(Pw0 + ln * 72 + rcol);
        bf16x8 ap1 = *(const bf16x8*)(Pw1 + ln * 72 + rcol);
        accl[0] = __builtin_amdgcn_mfma_f32_16x16x32_bf16(ap0, ones, accl[0], 0, 0, 0);
        accl[1] = __builtin_amdgcn_mfma_f32_16x16x32_bf16(ap1, ones, accl[1], 0, 0, 0);
#pragma unroll
        for (int t2 = 0; t2 < 4; ++t2) {
          bf16x8 bv = *(const bf16x8*)(Vc + (t2 * 16 + ln) * 64 +
                                       ((ks2 * 32 + quad * 8) ^ swL));
          acc[0][t2] = __builtin_amdgcn_mfma_f32_16x16x32_bf16(ap0, bv, acc[0][t2], 0, 0, 0);
          acc[1][t2] = __builtin_amdgcn_mfma_f32_16x16x32_bf16(ap1, bv, acc[1][t2], 0, 0, 0);
        }
      }
    }
    __syncthreads();
  }

  const long b = bh >> 4;
  const int h = bh & 15;
#pragma unroll
  for (int mt = 0; mt < 2; ++mt) {
#pragma unroll
    for (int r = 0; r < 4; ++r) {
      float inv = 1.0f / accl[mt][r];
      const int qq = q0 + wave * 32 + mt * 16 + quad * 4 + r;
#pragma unroll
      for (int t2 = 0; t2 < 4; ++t2)
        Y[(((b * S_LEN + qq) * NHEAD) + h) * HDIM + t2 * 16 + ln] = f2b(acc[mt][t2][r] * inv);
    }
  }
}

extern "C" void kernel_launch(void* const* d_in, const int* in_sizes, int n_in,
                              void* d_out, int out_size, void* d_ws, size_t ws_size,
                              hipStream_t stream) {
  const float* x  = (const float*)d_in[0];
  const float* Wq = (const float*)d_in[1];
  const float* Wk = (const float*)d_in[2];
  const float* Wv = (const float*)d_in[3];
  const float* Wo = (const float*)d_in[4];
  const float* bo = (const float*)d_in[5];
  float* out = (float*)d_out;

  const size_t XE = (size_t)8192 * EMB;  // 8388608
  ushort* ws    = (ushort*)d_ws;
  ushort* xb    = ws;
  ushort* Wtqkv = xb + XE;
  ushort* Wto   = Wtqkv + 3 * 1048576;
  ushort* Qb    = Wto + 1048576;
  ushort* Kb    = Qb + XE;
  ushort* Vtb   = Kb + XE;
  ushort* Yb    = xb;  // alias: xb dead after QKV GEMM

  const float SCALE_Q = 1.4426950408889634f / 8.0f;  // log2(e)/sqrt(D)

  prep_kernel<<<dim3(32, 32, 5), 256, 0, stream>>>(
      x, Wq, Wk, Wv, Wo, xb, Wtqkv, Wtqkv + 1048576, Wtqkv + 2097152, Wto, SCALE_Q);

  // QKV: M=8192, N=3072 -> grid 64x12 = 768 blocks = exactly 3 CU-waves
  gemm8_kernel<0><<<dim3(64, 12), 512, 0, stream>>>(xb, Wtqkv, Qb, Kb, Vtb,
                                                    nullptr, nullptr);
  attn_kernel<<<dim3(64, 16), 256, 0, stream>>>(Qb, Kb, Vtb, Yb);
  // out-proj: M=8192, N=1024 -> grid 64x4 = 256 blocks = exactly 1 CU-wave
  gemm8_kernel<1><<<dim3(64, 4), 512, 0, stream>>>(Yb, Wto, nullptr, nullptr,
                                                   nullptr, out, bo);
}

// Round 6
// 218.282 us; speedup vs baseline: 1.0716x; 1.0716x over previous
//
#include <hip/hip_runtime.h>

typedef __bf16 bf16x8 __attribute__((ext_vector_type(8)));
typedef float f32x4 __attribute__((ext_vector_type(4)));
typedef float f32x16 __attribute__((ext_vector_type(16)));
typedef unsigned short u16x8 __attribute__((ext_vector_type(8)));
typedef unsigned int u32x4 __attribute__((ext_vector_type(4)));

#define S_LEN 2048
#define NHEAD 16
#define HDIM  64
#define EMB   1024

__device__ __forceinline__ ushort f2b(float v) {
  union { float f; unsigned u; } x; x.f = v;
  unsigned r = (x.u + 0x7fffu + ((x.u >> 16) & 1u)) >> 16;
  return (ushort)r;
}

__device__ __forceinline__ ushort f2b_trunc(float v) {
  union { float f; unsigned u; } x; x.f = v;
  return (ushort)(x.u >> 16);
}

// pack two f32 -> u32 of 2 bf16 (truncation, same rounding as old P path)
__device__ __forceinline__ unsigned pk2(float lo, float hi) {
  union { float f; unsigned u; } a, b; a.f = lo; b.f = hi;
  return (b.u & 0xffff0000u) | (a.u >> 16);
}

// async global->LDS, 16B per lane; LDS dest = wave-uniform base + lane*16
typedef const __attribute__((address_space(1))) unsigned int* gp1_t;
typedef __attribute__((address_space(3))) unsigned int* lp3_t;
__device__ __forceinline__ void gld16(const ushort* g, const ushort* l) {
  __builtin_amdgcn_global_load_lds((gp1_t)(unsigned long long)(uintptr_t)g,
                                   (lp3_t)(unsigned int)(uintptr_t)l, 16, 0, 0);
}

__device__ __forceinline__ void barf() {
  asm volatile("" ::: "memory");
  __builtin_amdgcn_s_barrier();
  asm volatile("" ::: "memory");
}

// ---------- fused prep: cast x -> bf16 (z==4) + transpose/cast weights (z<4) ----------
__global__ __launch_bounds__(256) void prep_kernel(
    const float* __restrict__ x, const float* __restrict__ W0,
    const float* __restrict__ W1, const float* __restrict__ W2,
    const float* __restrict__ W3, ushort* __restrict__ xb,
    ushort* __restrict__ Wt0, ushort* __restrict__ Wt1,
    ushort* __restrict__ Wt2, ushort* __restrict__ Wt3, float scale0) {
  const int z = blockIdx.z;
  if (z == 4) {  // x cast: 1024 blocks x 8192 floats
    size_t base = ((size_t)(blockIdx.y * 32 + blockIdx.x)) * 8192 + threadIdx.x * 4;
#pragma unroll
    for (int i = 0; i < 8; ++i) {
      float4 v = *(const float4*)(x + base + i * 1024);
      ushort4 o;
      o.x = f2b(v.x); o.y = f2b(v.y); o.z = f2b(v.z); o.w = f2b(v.w);
      *(ushort4*)(xb + base + i * 1024) = o;
    }
    return;
  }
  __shared__ float t[32][33];
  const float* W = z == 0 ? W0 : (z == 1 ? W1 : (z == 2 ? W2 : W3));
  ushort* Wt = z == 0 ? Wt0 : (z == 1 ? Wt1 : (z == 2 ? Wt2 : Wt3));
  const float scale = z == 0 ? scale0 : 1.0f;
  int k0 = blockIdx.x * 32, n0 = blockIdx.y * 32;
  int c = threadIdx.x & 31, r0 = threadIdx.x >> 5;
#pragma unroll
  for (int i = 0; i < 4; ++i) {
    int r = r0 + i * 8;
    t[r][c] = W[(size_t)(k0 + r) * EMB + n0 + c];
  }
  __syncthreads();
#pragma unroll
  for (int i = 0; i < 4; ++i) {
    int r = r0 + i * 8;
    Wt[(size_t)(n0 + r) * EMB + k0 + c] = f2b(t[c][r] * scale);
  }
}

// ---------------- GEMM v5 (unchanged, passing) ----------------
template <int EPI>
__global__ __launch_bounds__(512, 2) void gemm8_kernel(
    const ushort* __restrict__ A, const ushort* __restrict__ Bt,
    ushort* __restrict__ outQ, ushort* __restrict__ outK, ushort* __restrict__ outVt,
    float* __restrict__ outF, const float* __restrict__ bias) {
  __shared__ ushort lds8[73728];  // 144 KiB
  const int tid = threadIdx.x;
  const int wave = tid >> 6, lane = tid & 63, ln = lane & 15, quad = lane >> 4;
  const int wm = wave >> 2, wn = wave & 3;
  const long m0 = (long)blockIdx.x * 128, n0 = (long)blockIdx.y * 256;
  constexpr int K = EMB, KT = K / 64;  // 16 K-tiles

  const int srow = tid >> 3;
  const int scol = ((tid & 7) ^ (srow & 7)) * 8;
  const ushort* srcA = A + (m0 + srow) * (long)K + scol;
  const ushort* srcB = Bt + (n0 + srow) * (long)K + scol;

#define STG_A(t, s)                                                            \
  do {                                                                         \
    gld16(srcA + (t) * 64,               lds8 + (s) * 8192 + tid * 8);         \
    gld16(srcA + (t) * 64 + 64 * K,      lds8 + (s) * 8192 + 4096 + tid * 8);  \
  } while (0)
#define STG_B(t, s)                                                            \
  do {                                                                         \
    gld16(srcB + (t) * 64,               lds8 + 24576 + (s) * 16384 + tid * 8);         \
    gld16(srcB + (t) * 64 + 64 * K,      lds8 + 24576 + (s) * 16384 + 4096 + tid * 8);  \
    gld16(srcB + (t) * 64 + 128 * K,     lds8 + 24576 + (s) * 16384 + 8192 + tid * 8);  \
    gld16(srcB + (t) * 64 + 192 * K,     lds8 + 24576 + (s) * 16384 + 12288 + tid * 8); \
  } while (0)

  const int sw = (ln & 7) * 8;

#define RD_A(F, kk, s)                                                         \
  do {                                                                         \
    const ushort* p_ = lds8 + (s) * 8192 + (wm * 64 + ln) * 64 +               \
                       (((kk) * 32 + quad * 8) ^ sw);                          \
    F[0] = *(const bf16x8*)p_;                                                 \
    F[1] = *(const bf16x8*)(p_ + 1024);                                        \
    F[2] = *(const bf16x8*)(p_ + 2048);                                        \
    F[3] = *(const bf16x8*)(p_ + 3072);                                        \
  } while (0)
#define RD_B(F, kk, s)                                                         \
  do {                                                                         \
    const ushort* p_ = lds8 + 24576 + (s) * 16384 + (wn * 64 + ln) * 64 +      \
                       (((kk) * 32 + quad * 8) ^ sw);                          \
    F[0] = *(const bf16x8*)p_;                                                 \
    F[1] = *(const bf16x8*)(p_ + 1024);                                        \
    F[2] = *(const bf16x8*)(p_ + 2048);                                        \
    F[3] = *(const bf16x8*)(p_ + 3072);                                        \
  } while (0)

#define MM16(AF, BF)                                                           \
  do {                                                                         \
    __builtin_amdgcn_s_setprio(1);                                             \
    _Pragma("unroll") for (int mt = 0; mt < 4; ++mt)                           \
        _Pragma("unroll") for (int nt = 0; nt < 4; ++nt)                       \
            acc[mt][nt] = __builtin_amdgcn_mfma_f32_16x16x32_bf16(             \
                AF[mt], BF[nt], acc[mt][nt], 0, 0, 0);                         \
    __builtin_amdgcn_s_setprio(0);                                             \
  } while (0)

  f32x4 acc[4][4] = {};
  bf16x8 afP[4], bfP[4], afN[4], bfN[4];

  STG_A(0, 0); STG_B(0, 0);
  STG_A(1, 1); STG_B(1, 1);
  asm volatile("s_waitcnt vmcnt(6)" ::: "memory");
  barf();
  RD_A(afP, 0, 0); RD_B(bfP, 0, 0);

#define TILE_FULL(t, s, s1, s2)                                                \
  do {                                                                         \
    STG_A((t) + 2, s2);                                                        \
    RD_A(afN, 1, s); RD_B(bfN, 1, s);                                          \
    MM16(afP, bfP);                                                            \
    STG_B((t) + 2, s2);                                                        \
    asm volatile("s_waitcnt vmcnt(6) lgkmcnt(0)" ::: "memory");                \
    barf();                                                                    \
    RD_A(afP, 0, s1); RD_B(bfP, 0, s1);                                        \
    MM16(afN, bfN);                                                            \
  } while (0)

  for (int th = 0; th < 12; th += 3) {
    TILE_FULL(th, 0, 1, 2);
    TILE_FULL(th + 1, 1, 2, 0);
    TILE_FULL(th + 2, 2, 0, 1);
  }
  TILE_FULL(12, 0, 1, 2);
  TILE_FULL(13, 1, 2, 0);
  RD_A(afN, 1, 2); RD_B(bfN, 1, 2);
  MM16(afP, bfP);
  asm volatile("s_waitcnt vmcnt(0) lgkmcnt(0)" ::: "memory");
  barf();
  RD_A(afP, 0, 0); RD_B(bfP, 0, 0);
  MM16(afN, bfN);
  RD_A(afN, 1, 0); RD_B(bfN, 1, 0);
  MM16(afP, bfP);
  MM16(afN, bfN);

  if (EPI == 0) {
    const int sel = (int)(n0 >> 10);
    if (sel == 2) {
#pragma unroll
      for (int mt = 0; mt < 4; ++mt) {
        const long mbase = m0 + wm * 64 + mt * 16 + quad * 4;
        const long bb = mbase >> 11, s = mbase & 2047;
#pragma unroll
        for (int nt = 0; nt < 4; ++nt) {
          const int nn = (int)((n0 & 1023) + wn * 64 + nt * 16 + ln);
          const int h = nn >> 6, d = nn & 63;
          uint2 val;
          val.x = (unsigned)f2b(acc[mt][nt][0]) | ((unsigned)f2b(acc[mt][nt][1]) << 16);
          val.y = (unsigned)f2b(acc[mt][nt][2]) | ((unsigned)f2b(acc[mt][nt][3]) << 16);
          *(uint2*)(outVt + (((bb * NHEAD + h) * (long)HDIM + d) * S_LEN) + s) = val;
        }
      }
    } else {
      ushort* dst = sel == 0 ? outQ : outK;
#pragma unroll
      for (int mt = 0; mt < 4; ++mt) {
#pragma unroll
        for (int nt = 0; nt < 4; ++nt) {
          const int nn = (int)((n0 & 1023) + wn * 64 + nt * 16 + ln);
          const int h = nn >> 6, d = nn & 63;
#pragma unroll
          for (int r = 0; r < 4; ++r) {
            const long m = m0 + wm * 64 + mt * 16 + quad * 4 + r;
            const long bb = m >> 11, s = m & 2047;
            dst[(((bb * NHEAD + h) * S_LEN) + s) * HDIM + d] = f2b(acc[mt][nt][r]);
          }
        }
      }
    }
  } else {
#pragma unroll
    for (int mt = 0; mt < 4; ++mt) {
#pragma unroll
      for (int nt = 0; nt < 4; ++nt) {
        const long n = n0 + wn * 64 + nt * 16 + ln;
        const float bv = bias[n];
#pragma unroll
        for (int r = 0; r < 4; ++r) {
          const long m = m0 + wm * 64 + mt * 16 + quad * 4 + r;
          outF[m * (long)EMB + n] = acc[mt][nt][r] + bv;
        }
      }
    }
  }
#undef TILE_FULL
#undef MM16
#undef RD_B
#undef RD_A
#undef STG_B
#undef STG_A
}

// ---------------- flash attention, v6: swapped-QK 32x32 + in-register P ----------------
// Q,K: [bh][s][d] bf16 (Q pre-scaled by log2e/8 via Wq).  Vt: [bh][d][s] bf16.
// Y: [b][s][h][d] bf16.
// T12 structure (m214-verified layout): sT = mfma_32x32x16(K_frag, Q_frag)
// puts P[q=lane&31][key=(r&3)+8*(r>>2)+4*hi] in registers; exp+pack to bf16
// pairs; 8 shfl_xor(32) + 16 selects build the PV A-fragments
// A[row=q][k=hi*8+j]; PV and ones-MFMA row-sum consume them directly.
// Removes per thread-tile: 32 ds_write_b16 + 4 ds_read_b128 + 2 fences +
// the 18KB Ps buffer (LDS 50->32KB).  K/V staging/swizzle unchanged from v5.
__global__ __launch_bounds__(256, 3) void attn_kernel(const ushort* __restrict__ Q,
                                                      const ushort* __restrict__ Kg,
                                                      const ushort* __restrict__ Vt,
                                                      ushort* __restrict__ Y) {
  __shared__ alignas(16) ushort Ks[2][4096];  // [buf][key 64][d 64] swizzled
  __shared__ alignas(16) ushort Vs[2][4096];  // [buf][d 64][key 64] swizzled
  const int tid = threadIdx.x;
  const int wave = tid >> 6, lane = tid & 63;
  const int l31 = lane & 31, hi = lane >> 5;
  const int bh = blockIdx.x;
  const int qb = 15 - (int)blockIdx.y;  // LPT: longest q-blocks first
  const int q0 = qb * 128;
  const size_t base = (size_t)bh * S_LEN * HDIM;
  const int ntiles = 2 * qb + 2;

  const u16x8 ob = {0x3F80, 0x3F80, 0x3F80, 0x3F80, 0x3F80, 0x3F80, 0x3F80, 0x3F80};
  const bf16x8 ones = __builtin_bit_cast(bf16x8, ob);

  // Q fragments: B-operand of swapped QK = A-layout data Q[q=l31][d=dsub*16+hi*8..+7]
  bf16x8 qf[4];
#pragma unroll
  for (int dsub = 0; dsub < 4; ++dsub)
    qf[dsub] = *(const bf16x8*)(Q + base + (size_t)(q0 + wave * 32 + l31) * HDIM +
                                dsub * 16 + hi * 8);

  f32x16 acc0 = {}, acc1 = {}, accl = {};

  // ---- staging: pre-swizzled global source, linear LDS dest (rule #21) ----
  const int srow = tid >> 3;                        // 0..31
  const int scc  = ((tid & 7) ^ (srow & 7)) * 8;    // swizzled ushort col
  const ushort* KgS = Kg + base + (size_t)srow * HDIM + scc;
  const ushort* VgS = Vt + base + (size_t)srow * S_LEN + scc;

  {
    gld16(KgS,                       &Ks[0][0] + tid * 8);
    gld16(KgS + 32 * HDIM,           &Ks[0][0] + 2048 + tid * 8);
    gld16(VgS,                       &Vs[0][0] + tid * 8);
    gld16(VgS + 32 * (size_t)S_LEN,  &Vs[0][0] + 2048 + tid * 8);
  }
  __syncthreads();

  const int swL = (lane & 7) * 8;   // K/V read swizzle (row&7 == lane&7)
  const int qbase = q0 + wave * 32;

  for (int kt = 0; kt < ntiles; ++kt) {
    const int cur = kt & 1;
    const int k0 = kt * 64;
    if (kt + 1 < ntiles) {
      const int nb = cur ^ 1;
      const size_t k1 = (size_t)(k0 + 64);
      gld16(KgS + k1 * HDIM,                  &Ks[nb][0] + tid * 8);
      gld16(KgS + (k1 + 32) * HDIM,           &Ks[nb][0] + 2048 + tid * 8);
      gld16(VgS + k1,                         &Vs[nb][0] + tid * 8);
      gld16(VgS + 32 * (size_t)S_LEN + k1,    &Vs[nb][0] + 2048 + tid * 8);
    }
    const ushort* Kc = &Ks[cur][0];
    const ushort* Vc = &Vs[cur][0];

    if (k0 < qbase + 32) {
      // ---- QK^T swapped: sT[keyblk] = K·Q^T, layout col=q(l31),
      //      row=key=(r&3)+8*(r>>2)+4*hi (+keyblk*32) ----
      f32x16 sT0 = {}, sT1 = {};
#pragma unroll
      for (int dsub = 0; dsub < 4; ++dsub) {
        const int c = (dsub * 16 + hi * 8) ^ swL;
        bf16x8 kf0 = *(const bf16x8*)(Kc + l31 * 64 + c);
        bf16x8 kf1 = *(const bf16x8*)(Kc + (32 + l31) * 64 + c);
        sT0 = __builtin_amdgcn_mfma_f32_32x32x16_bf16(kf0, qf[dsub], sT0, 0, 0, 0);
        sT1 = __builtin_amdgcn_mfma_f32_32x32x16_bf16(kf1, qf[dsub], sT1, 0, 0, 0);
      }

      if (k0 + 63 > qbase) {  // diagonal region: causal mask
        const int rowq = qbase + l31;
#pragma unroll
        for (int r = 0; r < 16; ++r) {
          const int key = k0 + ((r & 3) + 8 * (r >> 2)) + 4 * hi;
          if (key > rowq) sT0[r] = -3.0e38f;
          if (key + 32 > rowq) sT1[r] = -3.0e38f;
        }
      }

      // ---- exp + pack pairs (keys kb,kb+1 -> one u32 of 2 bf16) ----
      unsigned pw0[8], pw1[8];
#pragma unroll
      for (int i = 0; i < 8; ++i) {
        pw0[i] = pk2(__builtin_amdgcn_exp2f(sT0[2 * i]),
                     __builtin_amdgcn_exp2f(sT0[2 * i + 1]));
        pw1[i] = pk2(__builtin_amdgcn_exp2f(sT1[2 * i]),
                     __builtin_amdgcn_exp2f(sT1[2 * i + 1]));
      }

      // ---- per 32-key block: 4 shfl_xor(32) exchanges + 2 PV A-frags ----
#define KEYBLK(PW, KSQ0)                                                       \
  do {                                                                         \
    const unsigned e0 = (unsigned)__shfl_xor((int)(hi ? PW[0] : PW[2]), 32, 64); \
    const unsigned e1 = (unsigned)__shfl_xor((int)(hi ? PW[1] : PW[3]), 32, 64); \
    const unsigned e2 = (unsigned)__shfl_xor((int)(hi ? PW[4] : PW[6]), 32, 64); \
    const unsigned e3 = (unsigned)__shfl_xor((int)(hi ? PW[5] : PW[7]), 32, 64); \
    u32x4 fwA, fwB;                                                            \
    fwA[0] = hi ? e0 : PW[0]; fwA[1] = hi ? e1 : PW[1];                        \
    fwA[2] = hi ? PW[2] : e0; fwA[3] = hi ? PW[3] : e1;                        \
    fwB[0] = hi ? e2 : PW[4]; fwB[1] = hi ? e3 : PW[5];                        \
    fwB[2] = hi ? PW[6] : e2; fwB[3] = hi ? PW[7] : e3;                        \
    bf16x8 paA = __builtin_bit_cast(bf16x8, fwA);                              \
    bf16x8 paB = __builtin_bit_cast(bf16x8, fwB);                              \
    accl = __builtin_amdgcn_mfma_f32_32x32x16_bf16(paA, ones, accl, 0, 0, 0);  \
    accl = __builtin_amdgcn_mfma_f32_32x32x16_bf16(paB, ones, accl, 0, 0, 0);  \
    {                                                                          \
      const int vcA = (((KSQ0)) * 16 + hi * 8) ^ swL;                          \
      bf16x8 va0 = *(const bf16x8*)(Vc + l31 * 64 + vcA);                      \
      bf16x8 va1 = *(const bf16x8*)(Vc + (32 + l31) * 64 + vcA);               \
      acc0 = __builtin_amdgcn_mfma_f32_32x32x16_bf16(paA, va0, acc0, 0, 0, 0); \
      acc1 = __builtin_amdgcn_mfma_f32_32x32x16_bf16(paA, va1, acc1, 0, 0, 0); \
      const int vcB = (((KSQ0) + 1) * 16 + hi * 8) ^ swL;                      \
      bf16x8 vb0 = *(const bf16x8*)(Vc + l31 * 64 + vcB);                      \
      bf16x8 vb1 = *(const bf16x8*)(Vc + (32 + l31) * 64 + vcB);               \
      acc0 = __builtin_amdgcn_mfma_f32_32x32x16_bf16(paB, vb0, acc0, 0, 0, 0); \
      acc1 = __builtin_amdgcn_mfma_f32_32x32x16_bf16(paB, vb1, acc1, 0, 0, 0); \
    }                                                                          \
  } while (0)

      KEYBLK(pw0, 0);
      KEYBLK(pw1, 2);
#undef KEYBLK
    }
    __syncthreads();
  }

  const long b = bh >> 4;
  const int h = bh & 15;
#pragma unroll
  for (int r = 0; r < 16; ++r) {
    const float inv = 1.0f / accl[r];
    const int qq = q0 + wave * 32 + ((r & 3) + 8 * (r >> 2)) + 4 * hi;
    ushort* yp = Y + (((b * S_LEN + qq) * NHEAD) + h) * HDIM;
    yp[l31]      = f2b(acc0[r] * inv);
    yp[32 + l31] = f2b(acc1[r] * inv);
  }
}

extern "C" void kernel_launch(void* const* d_in, const int* in_sizes, int n_in,
                              void* d_out, int out_size, void* d_ws, size_t ws_size,
                              hipStream_t stream) {
  const float* x  = (const float*)d_in[0];
  const float* Wq = (const float*)d_in[1];
  const float* Wk = (const float*)d_in[2];
  const float* Wv = (const float*)d_in[3];
  const float* Wo = (const float*)d_in[4];
  const float* bo = (const float*)d_in[5];
  float* out = (float*)d_out;

  const size_t XE = (size_t)8192 * EMB;  // 8388608
  ushort* ws    = (ushort*)d_ws;
  ushort* xb    = ws;
  ushort* Wtqkv = xb + XE;
  ushort* Wto   = Wtqkv + 3 * 1048576;
  ushort* Qb    = Wto + 1048576;
  ushort* Kb    = Qb + XE;
  ushort* Vtb   = Kb + XE;
  ushort* Yb    = xb;  // alias: xb dead after QKV GEMM

  const float SCALE_Q = 1.4426950408889634f / 8.0f;  // log2(e)/sqrt(D)

  prep_kernel<<<dim3(32, 32, 5), 256, 0, stream>>>(
      x, Wq, Wk, Wv, Wo, xb, Wtqkv, Wtqkv + 1048576, Wtqkv + 2097152, Wto, SCALE_Q);

  // QKV: M=8192, N=3072 -> grid 64x12 = 768 blocks = exactly 3 CU-waves
  gemm8_kernel<0><<<dim3(64, 12), 512, 0, stream>>>(xb, Wtqkv, Qb, Kb, Vtb,
                                                    nullptr, nullptr);
  attn_kernel<<<dim3(64, 16), 256, 0, stream>>>(Qb, Kb, Vtb, Yb);
  // out-proj: M=8192, N=1024 -> grid 64x4 = 256 blocks = exactly 1 CU-wave
  gemm8_kernel<1><<<dim3(64, 4), 512, 0, stream>>>(Yb, Wto, nullptr, nullptr,
                                                   nullptr, out, bo);
}